// Round 2
// baseline (373.036 us; speedup 1.0000x reference)
//
#include <hip/hip_runtime.h>
#include <hip/hip_bf16.h>

// Problem constants (MultiHeadAttention: S=2048, B=2, D=1024, H=16, dk=64)
#define S_LEN 2048
#define BATCH 2
#define DMODEL 1024
#define NHEAD 16
#define DK 64

typedef __bf16 bf16_t;
typedef bf16_t bf16x4 __attribute__((ext_vector_type(4)));
typedef bf16_t bf16x8 __attribute__((ext_vector_type(8)));
typedef float floatx4 __attribute__((ext_vector_type(4)));

// ---------------------------------------------------------------------------
// Kernel 0: detect mask element encoding + compute per-batch valid lengths.
// attn_mask[0][1] is always True (triu k=1) -> sniff element byte width.
// key_padding_mask is arange >= length  ->  length = S - count(True).
// ---------------------------------------------------------------------------
__global__ void prep_lens(const unsigned char* __restrict__ am,
                          const unsigned char* __restrict__ kpm,
                          int* __restrict__ lens)
{
    __shared__ int stride_s;
    __shared__ int cnt[BATCH];
    const int t = threadIdx.x;
    if (t == 0) {
        int st;
        if (am[1]) st = 1;                 // u8 / bool
        else if (am[2] | am[3]) st = 2;    // 16-bit encodings
        else st = 4;                       // int32 or fp32
        stride_s = st;
    }
    if (t < BATCH) cnt[t] = 0;
    __syncthreads();
    const int st = stride_s;
    for (int idx = t; idx < BATCH * S_LEN; idx += blockDim.x) {
        int nz = 0;
        for (int c = 0; c < st; c++) nz |= kpm[idx * st + c];
        if (nz) atomicAdd(&cnt[idx / S_LEN], 1);
    }
    __syncthreads();
    if (t < BATCH) lens[t] = S_LEN - cnt[t];
}

// ---------------------------------------------------------------------------
// Kernel 1: convert f32 inputs -> bf16 workspace (query,key,value,Wq,Wk,Wv,Wo).
// Layout in out: [q 4M][k 4M][v 4M][wq 1M][wk 1M][wv 1M][wo 1M]  (elements)
// ---------------------------------------------------------------------------
#define SEG  ((size_t)S_LEN * BATCH * DMODEL)   // 4,194,304
#define WSEG ((size_t)DMODEL * DMODEL)          // 1,048,576
#define CVT_TOT (3 * SEG + 4 * WSEG)            // 16,777,216

__global__ void cvt_all(const float* __restrict__ q, const float* __restrict__ k,
                        const float* __restrict__ v, const float* __restrict__ wq,
                        const float* __restrict__ wk, const float* __restrict__ wv,
                        const float* __restrict__ wo, bf16_t* __restrict__ out)
{
    size_t i4 = ((size_t)blockIdx.x * blockDim.x + threadIdx.x) * 4;
    const size_t stride = (size_t)gridDim.x * blockDim.x * 4;
    for (; i4 < CVT_TOT; i4 += stride) {
        const float* src;
        size_t off;
        if (i4 < SEG)                    { src = q;  off = i4; }
        else if (i4 < 2 * SEG)           { src = k;  off = i4 - SEG; }
        else if (i4 < 3 * SEG)           { src = v;  off = i4 - 2 * SEG; }
        else if (i4 < 3 * SEG + WSEG)    { src = wq; off = i4 - 3 * SEG; }
        else if (i4 < 3 * SEG + 2 * WSEG){ src = wk; off = i4 - (3 * SEG + WSEG); }
        else if (i4 < 3 * SEG + 3 * WSEG){ src = wv; off = i4 - (3 * SEG + 2 * WSEG); }
        else                             { src = wo; off = i4 - (3 * SEG + 3 * WSEG); }
        const float4 x = *(const float4*)(src + off);
        bf16x4 r;
        r[0] = (bf16_t)x.x; r[1] = (bf16_t)x.y; r[2] = (bf16_t)x.z; r[3] = (bf16_t)x.w;
        *(bf16x4*)(out + i4) = r;
    }
}

// ---------------------------------------------------------------------------
// GEMM:  C[m][n] = sum_k A[m][k] * W[n][k] + bias[n]   (bf16 in, f32 acc)
// 128x128 block tile, 4 waves (each 64x64 = 4x4 MFMA 16x16x32 tiles), BK=32,
// global_load_lds width=16 staging (m97 structure). bias is f32.
// MODE 0: C row-major [M][N]            (final out, f32)
// MODE 1: scatter to [B,H,S,dk] bf16    (Q, K)
// MODE 2: scatter to [B,H,dk,S] bf16    (V transposed for PV fragment reads)
// ---------------------------------------------------------------------------
template <int MODE, typename OutT>
__global__ __launch_bounds__(256, 2)
void gemm_bt(const bf16_t* __restrict__ A, const bf16_t* __restrict__ W,
             const float* __restrict__ bias, OutT* __restrict__ C,
             int M, int N, int K)
{
    __shared__ bf16_t As[128 * 32];
    __shared__ bf16_t Bs[128 * 32];

    const int t    = threadIdx.x;
    const int wave = t >> 6;
    const int lane = t & 63;
    const int l15  = lane & 15;
    const int quad = lane >> 4;

    const int mBase = blockIdx.y * 128;
    const int nBase = blockIdx.x * 128;
    const int wRow  = (wave >> 1) * 64;
    const int wCol  = (wave & 1) * 64;

    floatx4 acc[4][4];
#pragma unroll
    for (int i = 0; i < 4; i++)
#pragma unroll
        for (int j = 0; j < 4; j++) acc[i][j] = (floatx4){0.f, 0.f, 0.f, 0.f};

    for (int k0 = 0; k0 < K; k0 += 32) {
#pragma unroll
        for (int c = 0; c < 2; c++) {
            const int chunk = c * 256 + t;        // 0..511
            const int row   = chunk >> 2;
            const int col   = (chunk & 3) * 8;
            const bf16_t* gA = A + (size_t)(mBase + row) * K + k0 + col;
            const bf16_t* gB = W + (size_t)(nBase + row) * K + k0 + col;
            bf16_t* lA = As + (c * 256 + wave * 64) * 8;   // wave-uniform base
            bf16_t* lB = Bs + (c * 256 + wave * 64) * 8;
            __builtin_amdgcn_global_load_lds(
                (const __attribute__((address_space(1))) void*)gA,
                (__attribute__((address_space(3))) void*)lA, 16, 0, 0);
            __builtin_amdgcn_global_load_lds(
                (const __attribute__((address_space(1))) void*)gB,
                (__attribute__((address_space(3))) void*)lB, 16, 0, 0);
        }
        __syncthreads();

        bf16x8 af[4], bfr[4];
#pragma unroll
        for (int mi = 0; mi < 4; mi++)
            af[mi] = *(const bf16x8*)(As + (wRow + mi * 16 + l15) * 32 + quad * 8);
#pragma unroll
        for (int ni = 0; ni < 4; ni++)
            bfr[ni] = *(const bf16x8*)(Bs + (wCol + ni * 16 + l15) * 32 + quad * 8);
#pragma unroll
        for (int mi = 0; mi < 4; mi++)
#pragma unroll
            for (int ni = 0; ni < 4; ni++)
                acc[mi][ni] = __builtin_amdgcn_mfma_f32_16x16x32_bf16(
                    af[mi], bfr[ni], acc[mi][ni], 0, 0, 0);
        __syncthreads();
    }

    float bv[4];
#pragma unroll
    for (int ni = 0; ni < 4; ni++)
        bv[ni] = bias[nBase + wCol + ni * 16 + l15];

#pragma unroll
    for (int mi = 0; mi < 4; mi++) {
#pragma unroll
        for (int ni = 0; ni < 4; ni++) {
            const int n = nBase + wCol + ni * 16 + l15;
#pragma unroll
            for (int j = 0; j < 4; j++) {
                const int m = mBase + wRow + mi * 16 + quad * 4 + j;
                const float v = acc[mi][ni][j] + bv[ni];
                size_t off;
                if (MODE == 0) {
                    off = (size_t)m * N + n;
                } else {
                    const int s = m >> 1, b = m & 1;       // m = s*B + b, B=2
                    const int h = n >> 6, i = n & 63;      // n = h*dk + i
                    if (MODE == 1)
                        off = ((size_t)(b * NHEAD + h) * S_LEN + s) * DK + i;
                    else
                        off = ((size_t)(b * NHEAD + h) * DK + i) * S_LEN + s;
                }
                C[off] = (OutT)v;
            }
        }
    }
}

// ---------------------------------------------------------------------------
// Flash-style causal attention with key-padding.
// Grid: (S/64 q-tiles, B*H). Block: 256 thr = 4 waves; wave w owns 16 q rows.
// Q: [B,H,S,dk]  K: [B,H,S,dk]  V: [B,H,dk,S] (transposed)  O: [S,B,D] bf16.
// ---------------------------------------------------------------------------
__global__ __launch_bounds__(256, 2)
void attn(const bf16_t* __restrict__ qw, const bf16_t* __restrict__ kw,
          const bf16_t* __restrict__ vw, bf16_t* __restrict__ ow,
          const int* __restrict__ lens)
{
    __shared__ bf16_t Ks[64 * 64];          // [key][dk]
    __shared__ bf16_t Vs[64 * 64];          // [dk][key]
    __shared__ bf16_t Ps[4 * 16 * 64];      // per-wave P scratch [qrow][key]

    const int t    = threadIdx.x;
    const int wave = t >> 6;
    const int lane = t & 63;
    const int l15  = lane & 15;
    const int quad = lane >> 4;

    const int bh    = blockIdx.y;           // b*H + h
    const int b     = bh >> 4;              // H = 16
    const int qTile = blockIdx.x;
    const int qBase = qTile * 64;
    const int len   = lens[b];

    // Q fragments for this wave's 16 rows (A-layout: [m=l15][k=quad*8+j])
    const bf16_t* Qg = qw + ((size_t)bh * S_LEN + qBase + wave * 16) * DK;
    const bf16x8 qa0 = *(const bf16x8*)(Qg + l15 * DK + quad * 8);
    const bf16x8 qa1 = *(const bf16x8*)(Qg + l15 * DK + 32 + quad * 8);

    floatx4 O[4];
#pragma unroll
    for (int i = 0; i < 4; i++) O[i] = (floatx4){0.f, 0.f, 0.f, 0.f};
    float mrow[4], lrow[4];
#pragma unroll
    for (int j = 0; j < 4; j++) { mrow[j] = -1e30f; lrow[j] = 0.f; }

    const int ktEnd = min(qTile, (len - 1) >> 6);   // len >= S/2 >= 1024

    for (int kt = 0; kt <= ktEnd; kt++) {
        const int ktBase = kt * 64;
        // stage K tile (contiguous 8KB) and V tile (64 rows of 128B)
        {
            const int4* srcK = (const int4*)(kw + ((size_t)bh * S_LEN + ktBase) * DK);
            int4* dstK = (int4*)Ks;
            dstK[t]       = srcK[t];
            dstK[256 + t] = srcK[256 + t];
#pragma unroll
            for (int c = 0; c < 2; c++) {
                const int chunk = c * 256 + t;       // 0..511
                const int row   = chunk >> 3;        // dk row
                const int col   = (chunk & 7) * 8;   // key col
                *(int4*)(Vs + row * 64 + col) =
                    *(const int4*)(vw + ((size_t)bh * DK + row) * S_LEN + ktBase + col);
            }
        }
        __syncthreads();

        // scores S = Q K^T (16 q rows x 64 keys per wave)
        floatx4 sc[4];
#pragma unroll
        for (int ni = 0; ni < 4; ni++) {
            const bf16x8 kf0 = *(const bf16x8*)(Ks + (ni * 16 + l15) * 64 + quad * 8);
            const bf16x8 kf1 = *(const bf16x8*)(Ks + (ni * 16 + l15) * 64 + 32 + quad * 8);
            floatx4 z = (floatx4){0.f, 0.f, 0.f, 0.f};
            z = __builtin_amdgcn_mfma_f32_16x16x32_bf16(qa0, kf0, z, 0, 0, 0);
            z = __builtin_amdgcn_mfma_f32_16x16x32_bf16(qa1, kf1, z, 0, 0, 0);
            sc[ni] = z;
        }

        // scale + causal & padding mask; per-row tile max
        float tmax[4];
#pragma unroll
        for (int j = 0; j < 4; j++) tmax[j] = -1e30f;
#pragma unroll
        for (int ni = 0; ni < 4; ni++) {
            const int key = ktBase + ni * 16 + l15;
#pragma unroll
            for (int j = 0; j < 4; j++) {
                const int q = qBase + wave * 16 + quad * 4 + j;
                float s = sc[ni][j] * 0.125f;        // 1/sqrt(64)
                if (key > q || key >= len) s = -1e30f;
                sc[ni][j] = s;
                tmax[j] = fmaxf(tmax[j], s);
            }
        }
#pragma unroll
        for (int j = 0; j < 4; j++) {
            float v = tmax[j];
#pragma unroll
            for (int off = 8; off >= 1; off >>= 1)
                v = fmaxf(v, __shfl_xor(v, off, 16));
            tmax[j] = v;
        }

        float alpha[4], rsum[4];
#pragma unroll
        for (int j = 0; j < 4; j++) {
            const float mnew = fmaxf(mrow[j], tmax[j]);
            alpha[j] = __expf(mrow[j] - mnew);
            mrow[j] = mnew;
            rsum[j] = 0.f;
        }
#pragma unroll
        for (int ni = 0; ni < 4; ni++) {
#pragma unroll
            for (int j = 0; j < 4; j++) {
                const float p = __expf(sc[ni][j] - mrow[j]);
                sc[ni][j] = p;
                rsum[j] += p;
            }
        }
#pragma unroll
        for (int j = 0; j < 4; j++) {
            float v = rsum[j];
#pragma unroll
            for (int off = 8; off >= 1; off >>= 1)
                v += __shfl_xor(v, off, 16);
            lrow[j] = lrow[j] * alpha[j] + v;
        }
#pragma unroll
        for (int nd = 0; nd < 4; nd++)
#pragma unroll
            for (int j = 0; j < 4; j++) O[nd][j] *= alpha[j];

        // P: C-layout -> LDS -> A-layout (wave-local; DS pipe is in-order)
        bf16_t* Pw = Ps + wave * 1024;
#pragma unroll
        for (int ni = 0; ni < 4; ni++)
#pragma unroll
            for (int j = 0; j < 4; j++)
                Pw[(quad * 4 + j) * 64 + ni * 16 + l15] = (bf16_t)sc[ni][j];

        const bf16x8 pa0 = *(const bf16x8*)(Pw + l15 * 64 + quad * 8);
        const bf16x8 pa1 = *(const bf16x8*)(Pw + l15 * 64 + 32 + quad * 8);
#pragma unroll
        for (int nd = 0; nd < 4; nd++) {
            const bf16x8 vb0 = *(const bf16x8*)(Vs + (nd * 16 + l15) * 64 + quad * 8);
            const bf16x8 vb1 = *(const bf16x8*)(Vs + (nd * 16 + l15) * 64 + 32 + quad * 8);
            O[nd] = __builtin_amdgcn_mfma_f32_16x16x32_bf16(pa0, vb0, O[nd], 0, 0, 0);
            O[nd] = __builtin_amdgcn_mfma_f32_16x16x32_bf16(pa1, vb1, O[nd], 0, 0, 0);
        }
        __syncthreads();   // protect Ks/Vs before next stage
    }

    // write O / l  to [S, B, D]
#pragma unroll
    for (int nd = 0; nd < 4; nd++) {
        const int d = (bh & 15) * DK + nd * 16 + l15;   // h = bh % 16
#pragma unroll
        for (int j = 0; j < 4; j++) {
            const int q = qBase + wave * 16 + quad * 4 + j;
            const float v = O[nd][j] / lrow[j];
            ow[((size_t)q * BATCH + b) * DMODEL + d] = (bf16_t)v;
        }
    }
}

// ---------------------------------------------------------------------------
// Launch. Workspace (bf16 elements unless noted), total 56 MB + 8 B:
//   cvt region (16M):  q_bf | k_bf | v_bf | wq_bf | wk_bf | wv_bf | wo_bf
//   q_ws/k_ws/v_ws (12M): projected heads
//   o_ws (4M): attention output -- ALIASES q_bf (dead after proj GEMMs)
//   lens: int[2]
// ---------------------------------------------------------------------------
extern "C" void kernel_launch(void* const* d_in, const int* in_sizes, int n_in,
                              void* d_out, int out_size, void* d_ws, size_t ws_size,
                              hipStream_t stream)
{
    const float* query = (const float*)d_in[0];
    const float* key   = (const float*)d_in[1];
    const float* value = (const float*)d_in[2];
    const float* Wq = (const float*)d_in[3];
    const float* bq = (const float*)d_in[4];
    const float* Wk = (const float*)d_in[5];
    const float* bk = (const float*)d_in[6];
    const float* Wv = (const float*)d_in[7];
    const float* bv = (const float*)d_in[8];
    const float* Wo = (const float*)d_in[9];
    const float* bo = (const float*)d_in[10];
    const unsigned char* am  = (const unsigned char*)d_in[11];
    const unsigned char* kpm = (const unsigned char*)d_in[12];

    bf16_t* cvt   = (bf16_t*)d_ws;
    bf16_t* q_bf  = cvt;
    bf16_t* k_bf  = cvt + SEG;
    bf16_t* v_bf  = cvt + 2 * SEG;
    bf16_t* wq_bf = cvt + 3 * SEG;
    bf16_t* wk_bf = wq_bf + WSEG;
    bf16_t* wv_bf = wk_bf + WSEG;
    bf16_t* wo_bf = wv_bf + WSEG;
    bf16_t* q_ws  = cvt + CVT_TOT;
    bf16_t* k_ws  = q_ws + SEG;
    bf16_t* v_ws  = k_ws + SEG;
    bf16_t* o_ws  = q_bf;                    // alias: q_bf dead after proj GEMMs
    int*    lens  = (int*)(v_ws + SEG);

    prep_lens<<<1, 256, 0, stream>>>(am, kpm, lens);
    cvt_all<<<4096, 256, 0, stream>>>(query, key, value, Wq, Wk, Wv, Wo, cvt);

    dim3 g(DMODEL / 128, (S_LEN * BATCH) / 128), blk(256);
    gemm_bt<1, bf16_t><<<g, blk, 0, stream>>>(q_bf, wq_bf, bq, q_ws, S_LEN * BATCH, DMODEL, DMODEL);
    gemm_bt<1, bf16_t><<<g, blk, 0, stream>>>(k_bf, wk_bf, bk, k_ws, S_LEN * BATCH, DMODEL, DMODEL);
    gemm_bt<2, bf16_t><<<g, blk, 0, stream>>>(v_bf, wv_bf, bv, v_ws, S_LEN * BATCH, DMODEL, DMODEL);

    attn<<<dim3(S_LEN / 64, BATCH * NHEAD), blk, 0, stream>>>(q_ws, k_ws, v_ws, o_ws, lens);

    gemm_bt<0, float><<<g, blk, 0, stream>>>(o_ws, wo_bf, bo, (float*)d_out, S_LEN * BATCH, DMODEL, DMODEL);
}

// Round 3
// 357.621 us; speedup vs baseline: 1.0431x; 1.0431x over previous
//
#include <hip/hip_runtime.h>
#include <hip/hip_bf16.h>

// Problem constants (MultiHeadAttention: S=2048, B=2, D=1024, H=16, dk=64)
#define S_LEN 2048
#define BATCH 2
#define DMODEL 1024
#define NHEAD 16
#define DK 64

typedef __bf16 bf16_t;
typedef bf16_t bf16x4 __attribute__((ext_vector_type(4)));
typedef bf16_t bf16x8 __attribute__((ext_vector_type(8)));
typedef float floatx4 __attribute__((ext_vector_type(4)));

#define SEG  ((size_t)S_LEN * BATCH * DMODEL)   // 4,194,304
#define WSEG ((size_t)DMODEL * DMODEL)          // 1,048,576
#define CVT_TOT (3 * SEG + 4 * WSEG)            // 16,777,216

// Q pre-scale: 1/sqrt(dk) * log2(e)  -> softmax uses exp2 directly
#define QSCALE 0.180336879f

// ---------------------------------------------------------------------------
// Kernel 0: mask dtype sniff + per-batch valid lengths.
// ---------------------------------------------------------------------------
__global__ void prep_lens(const unsigned char* __restrict__ am,
                          const unsigned char* __restrict__ kpm,
                          int* __restrict__ lens)
{
    __shared__ int stride_s;
    __shared__ int cnt[BATCH];
    const int t = threadIdx.x;
    if (t == 0) {
        int st;
        if (am[1]) st = 1;
        else if (am[2] | am[3]) st = 2;
        else st = 4;
        stride_s = st;
    }
    if (t < BATCH) cnt[t] = 0;
    __syncthreads();
    const int st = stride_s;
    for (int idx = t; idx < BATCH * S_LEN; idx += blockDim.x) {
        int nz = 0;
        for (int c = 0; c < st; c++) nz |= kpm[idx * st + c];
        if (nz) atomicAdd(&cnt[idx / S_LEN], 1);
    }
    __syncthreads();
    if (t < BATCH) lens[t] = S_LEN - cnt[t];
}

// ---------------------------------------------------------------------------
// Kernel 1: f32 -> bf16 conversion of q,k,v,Wq,Wk,Wv,Wo into workspace.
// ---------------------------------------------------------------------------
__global__ void cvt_all(const float* __restrict__ q, const float* __restrict__ k,
                        const float* __restrict__ v, const float* __restrict__ wq,
                        const float* __restrict__ wk, const float* __restrict__ wv,
                        const float* __restrict__ wo, bf16_t* __restrict__ out)
{
    size_t i4 = ((size_t)blockIdx.x * blockDim.x + threadIdx.x) * 4;
    const size_t stride = (size_t)gridDim.x * blockDim.x * 4;
    for (; i4 < CVT_TOT; i4 += stride) {
        const float* src;
        size_t off;
        if (i4 < SEG)                    { src = q;  off = i4; }
        else if (i4 < 2 * SEG)           { src = k;  off = i4 - SEG; }
        else if (i4 < 3 * SEG)           { src = v;  off = i4 - 2 * SEG; }
        else if (i4 < 3 * SEG + WSEG)    { src = wq; off = i4 - 3 * SEG; }
        else if (i4 < 3 * SEG + 2 * WSEG){ src = wk; off = i4 - (3 * SEG + WSEG); }
        else if (i4 < 3 * SEG + 3 * WSEG){ src = wv; off = i4 - (3 * SEG + 2 * WSEG); }
        else                             { src = wo; off = i4 - (3 * SEG + 3 * WSEG); }
        const float4 x = *(const float4*)(src + off);
        bf16x4 r;
        r[0] = (bf16_t)x.x; r[1] = (bf16_t)x.y; r[2] = (bf16_t)x.z; r[3] = (bf16_t)x.w;
        *(bf16x4*)(out + i4) = r;
    }
}

// ---------------------------------------------------------------------------
// Fused Q/K/V projection GEMM. grid = (8, 32, 3); z selects {Q,K,V}.
// C[m][n] = (sum_k A[m][k] * W[n][k] + bias[n]) * (z==0 ? QSCALE : 1)
// z<2  -> scatter [B,H,S,dk] (Q gets QSCALE fold)
// z==2 -> scatter [B,H,dk,S] (V transposed)
// 128x128 tile, 4 waves, BK=32, global_load_lds width-16 staging (m97).
// ---------------------------------------------------------------------------
__global__ __launch_bounds__(256, 2)
void gemm_qkv(const bf16_t* __restrict__ Abase, const bf16_t* __restrict__ Wbase,
              const float* __restrict__ bq, const float* __restrict__ bk,
              const float* __restrict__ bv, bf16_t* __restrict__ Obase)
{
    __shared__ bf16_t As[128 * 32];
    __shared__ bf16_t Bs[128 * 32];

    const int z = blockIdx.z;
    const bf16_t* A = Abase + (size_t)z * SEG;
    const bf16_t* W = Wbase + (size_t)z * WSEG;
    const float* bias = (z == 0) ? bq : (z == 1) ? bk : bv;
    bf16_t* C = Obase + (size_t)z * SEG;

    const int t    = threadIdx.x;
    const int wave = t >> 6;
    const int lane = t & 63;
    const int l15  = lane & 15;
    const int quad = lane >> 4;

    const int mBase = blockIdx.y * 128;
    const int nBase = blockIdx.x * 128;
    const int wRow  = (wave >> 1) * 64;
    const int wCol  = (wave & 1) * 64;

    floatx4 acc[4][4];
#pragma unroll
    for (int i = 0; i < 4; i++)
#pragma unroll
        for (int j = 0; j < 4; j++) acc[i][j] = (floatx4){0.f, 0.f, 0.f, 0.f};

    for (int k0 = 0; k0 < DMODEL; k0 += 32) {
#pragma unroll
        for (int c = 0; c < 2; c++) {
            const int chunk = c * 256 + t;
            const int row   = chunk >> 2;
            const int col   = (chunk & 3) * 8;
            const bf16_t* gA = A + (size_t)(mBase + row) * DMODEL + k0 + col;
            const bf16_t* gB = W + (size_t)(nBase + row) * DMODEL + k0 + col;
            bf16_t* lA = As + (c * 256 + wave * 64) * 8;
            bf16_t* lB = Bs + (c * 256 + wave * 64) * 8;
            __builtin_amdgcn_global_load_lds(
                (const __attribute__((address_space(1))) void*)gA,
                (__attribute__((address_space(3))) void*)lA, 16, 0, 0);
            __builtin_amdgcn_global_load_lds(
                (const __attribute__((address_space(1))) void*)gB,
                (__attribute__((address_space(3))) void*)lB, 16, 0, 0);
        }
        __syncthreads();

        bf16x8 af[4], bfr[4];
#pragma unroll
        for (int mi = 0; mi < 4; mi++)
            af[mi] = *(const bf16x8*)(As + (wRow + mi * 16 + l15) * 32 + quad * 8);
#pragma unroll
        for (int ni = 0; ni < 4; ni++)
            bfr[ni] = *(const bf16x8*)(Bs + (wCol + ni * 16 + l15) * 32 + quad * 8);
#pragma unroll
        for (int mi = 0; mi < 4; mi++)
#pragma unroll
            for (int ni = 0; ni < 4; ni++)
                acc[mi][ni] = __builtin_amdgcn_mfma_f32_16x16x32_bf16(
                    af[mi], bfr[ni], acc[mi][ni], 0, 0, 0);
        __syncthreads();
    }

    const float scale = (z == 0) ? QSCALE : 1.0f;
    float bvv[4];
#pragma unroll
    for (int ni = 0; ni < 4; ni++)
        bvv[ni] = bias[nBase + wCol + ni * 16 + l15];

#pragma unroll
    for (int mi = 0; mi < 4; mi++) {
#pragma unroll
        for (int ni = 0; ni < 4; ni++) {
            const int n = nBase + wCol + ni * 16 + l15;
            const int h = n >> 6, i = n & 63;
#pragma unroll
            for (int j = 0; j < 4; j++) {
                const int m = mBase + wRow + mi * 16 + quad * 4 + j;
                const int s = m >> 1, b = m & 1;       // m = s*B + b, B=2
                const float v = (acc[mi][ni][j] + bvv[ni]) * scale;
                size_t off;
                if (z < 2)
                    off = ((size_t)(b * NHEAD + h) * S_LEN + s) * DK + i;
                else
                    off = ((size_t)(b * NHEAD + h) * DK + i) * S_LEN + s;
                C[off] = (bf16_t)v;
            }
        }
    }
}

// ---------------------------------------------------------------------------
// Flash-style causal attention. Grid (32, B*H), qTile REVERSED (longest
// first). 4 waves x 16 q-rows. LDS rows padded to 72 bf16 (conflict-free
// b128). Next K/V tile prefetched into VGPRs right after the barrier.
// Q is pre-scaled by QSCALE -> logits are in log2 units; softmax via exp2f.
// ---------------------------------------------------------------------------
__global__ __launch_bounds__(256, 4)
void attn(const bf16_t* __restrict__ qw, const bf16_t* __restrict__ kw,
          const bf16_t* __restrict__ vw, bf16_t* __restrict__ ow,
          const int* __restrict__ lens)
{
    __shared__ bf16_t Ks[64 * 72];          // [key][dk], padded
    __shared__ bf16_t Vs[64 * 72];          // [dk][key], padded
    __shared__ bf16_t Ps[4 * 16 * 72];      // per-wave P scratch, padded

    const int t    = threadIdx.x;
    const int wave = t >> 6;
    const int lane = t & 63;
    const int l15  = lane & 15;
    const int quad = lane >> 4;

    const int qTile = (int)(gridDim.x - 1 - blockIdx.x);   // longest first
    const int bh    = blockIdx.y;
    const int b     = bh >> 4;
    const int qBase = qTile * 64;
    const int len   = lens[b];

    const bf16_t* Qg = qw + ((size_t)bh * S_LEN + qBase + wave * 16) * DK;
    const bf16x8 qa0 = *(const bf16x8*)(Qg + l15 * DK + quad * 8);
    const bf16x8 qa1 = *(const bf16x8*)(Qg + l15 * DK + 32 + quad * 8);

    floatx4 O[4];
#pragma unroll
    for (int i = 0; i < 4; i++) O[i] = (floatx4){0.f, 0.f, 0.f, 0.f};
    float mrow[4], lrow[4];
#pragma unroll
    for (int j = 0; j < 4; j++) { mrow[j] = -1e30f; lrow[j] = 0.f; }

    const int ktEnd = min(qTile, (len - 1) >> 6);

    const bf16_t* kbase = kw + (size_t)bh * S_LEN * DK;
    const bf16_t* vbase = vw + (size_t)bh * DK * S_LEN;

    int4 kreg[2], vreg[2];
#pragma unroll
    for (int c = 0; c < 2; c++) {           // prefetch tile 0
        const int idx = c * 256 + t;
        kreg[c] = *(const int4*)(kbase + (size_t)idx * 8);
        vreg[c] = *(const int4*)(vbase + (size_t)(idx >> 3) * S_LEN + (idx & 7) * 8);
    }

    for (int kt = 0; kt <= ktEnd; kt++) {
        const int ktBase = kt * 64;
        // LDS fill from prefetch regs
#pragma unroll
        for (int c = 0; c < 2; c++) {
            const int idx = c * 256 + t, row = idx >> 3, col = (idx & 7) * 8;
            *(int4*)(Ks + row * 72 + col) = kreg[c];
            *(int4*)(Vs + row * 72 + col) = vreg[c];
        }
        __syncthreads();

        // issue next-tile prefetch (independent of compute below)
        if (kt < ktEnd) {
            const int nb = ktBase + 64;
#pragma unroll
            for (int c = 0; c < 2; c++) {
                const int idx = c * 256 + t;
                kreg[c] = *(const int4*)(kbase + (size_t)nb * DK + idx * 8);
                vreg[c] = *(const int4*)(vbase + (size_t)(idx >> 3) * S_LEN + nb + (idx & 7) * 8);
            }
        }

        // S = Q K^T  (logits already in log2 units)
        floatx4 sc[4];
#pragma unroll
        for (int ni = 0; ni < 4; ni++) {
            const bf16x8 kf0 = *(const bf16x8*)(Ks + (ni * 16 + l15) * 72 + quad * 8);
            const bf16x8 kf1 = *(const bf16x8*)(Ks + (ni * 16 + l15) * 72 + 32 + quad * 8);
            floatx4 zz = (floatx4){0.f, 0.f, 0.f, 0.f};
            zz = __builtin_amdgcn_mfma_f32_16x16x32_bf16(qa0, kf0, zz, 0, 0, 0);
            zz = __builtin_amdgcn_mfma_f32_16x16x32_bf16(qa1, kf1, zz, 0, 0, 0);
            sc[ni] = zz;
        }

        float tmax[4];
#pragma unroll
        for (int j = 0; j < 4; j++) tmax[j] = -1e30f;

        const bool needMask = (kt == qTile) || (ktBase + 64 > len);
        if (needMask) {
#pragma unroll
            for (int ni = 0; ni < 4; ni++) {
                const int key = ktBase + ni * 16 + l15;
#pragma unroll
                for (int j = 0; j < 4; j++) {
                    const int q = qBase + wave * 16 + quad * 4 + j;
                    float s = sc[ni][j];
                    if (key > q || key >= len) s = -1e30f;
                    sc[ni][j] = s;
                    tmax[j] = fmaxf(tmax[j], s);
                }
            }
        } else {
#pragma unroll
            for (int ni = 0; ni < 4; ni++)
#pragma unroll
                for (int j = 0; j < 4; j++)
                    tmax[j] = fmaxf(tmax[j], sc[ni][j]);
        }
#pragma unroll
        for (int j = 0; j < 4; j++) {
            float v = tmax[j];
#pragma unroll
            for (int off = 8; off >= 1; off >>= 1)
                v = fmaxf(v, __shfl_xor(v, off, 16));
            tmax[j] = v;
        }

        float alpha[4], rsum[4];
#pragma unroll
        for (int j = 0; j < 4; j++) {
            const float mnew = fmaxf(mrow[j], tmax[j]);
            alpha[j] = exp2f(mrow[j] - mnew);
            mrow[j] = mnew;
            rsum[j] = 0.f;
        }
#pragma unroll
        for (int ni = 0; ni < 4; ni++) {
#pragma unroll
            for (int j = 0; j < 4; j++) {
                const float p = exp2f(sc[ni][j] - mrow[j]);
                sc[ni][j] = p;
                rsum[j] += p;
            }
        }
#pragma unroll
        for (int j = 0; j < 4; j++) {
            float v = rsum[j];
#pragma unroll
            for (int off = 8; off >= 1; off >>= 1)
                v += __shfl_xor(v, off, 16);
            lrow[j] = lrow[j] * alpha[j] + v;
        }
#pragma unroll
        for (int nd = 0; nd < 4; nd++)
#pragma unroll
            for (int j = 0; j < 4; j++) O[nd][j] *= alpha[j];

        // P: C-layout -> LDS (padded) -> A-layout (wave-local)
        bf16_t* Pw = Ps + wave * 16 * 72;
#pragma unroll
        for (int ni = 0; ni < 4; ni++)
#pragma unroll
            for (int j = 0; j < 4; j++)
                Pw[(quad * 4 + j) * 72 + ni * 16 + l15] = (bf16_t)sc[ni][j];

        const bf16x8 pa0 = *(const bf16x8*)(Pw + l15 * 72 + quad * 8);
        const bf16x8 pa1 = *(const bf16x8*)(Pw + l15 * 72 + 32 + quad * 8);
#pragma unroll
        for (int nd = 0; nd < 4; nd++) {
            const bf16x8 vb0 = *(const bf16x8*)(Vs + (nd * 16 + l15) * 72 + quad * 8);
            const bf16x8 vb1 = *(const bf16x8*)(Vs + (nd * 16 + l15) * 72 + 32 + quad * 8);
            O[nd] = __builtin_amdgcn_mfma_f32_16x16x32_bf16(pa0, vb0, O[nd], 0, 0, 0);
            O[nd] = __builtin_amdgcn_mfma_f32_16x16x32_bf16(pa1, vb1, O[nd], 0, 0, 0);
        }
        __syncthreads();   // protect Ks/Vs before next LDS fill
    }

#pragma unroll
    for (int nd = 0; nd < 4; nd++) {
        const int d = (bh & 15) * DK + nd * 16 + l15;
#pragma unroll
        for (int j = 0; j < 4; j++) {
            const int q = qBase + wave * 16 + quad * 4 + j;
            const float v = O[nd][j] / lrow[j];
            ow[((size_t)q * BATCH + b) * DMODEL + d] = (bf16_t)v;
        }
    }
}

// ---------------------------------------------------------------------------
// Output projection GEMM, 128x64 tiles -> 512 blocks (2/CU).
// C[m][n] = sum_k A[m][k]*W[n][k] + bias[n], f32 out row-major [M][N].
// 4 waves, wave w owns rows w*32..w*32+31 x all 64 cols (2x4 acc).
// ---------------------------------------------------------------------------
__global__ __launch_bounds__(256, 2)
void gemm_o(const bf16_t* __restrict__ A, const bf16_t* __restrict__ W,
            const float* __restrict__ bias, float* __restrict__ C)
{
    __shared__ bf16_t As[128 * 32];
    __shared__ bf16_t Bs[64 * 32];

    const int t    = threadIdx.x;
    const int wave = t >> 6;
    const int lane = t & 63;
    const int l15  = lane & 15;
    const int quad = lane >> 4;

    const int mBase = blockIdx.y * 128;
    const int nBase = blockIdx.x * 64;
    const int wRow  = wave * 32;

    floatx4 acc[2][4];
#pragma unroll
    for (int i = 0; i < 2; i++)
#pragma unroll
        for (int j = 0; j < 4; j++) acc[i][j] = (floatx4){0.f, 0.f, 0.f, 0.f};

    for (int k0 = 0; k0 < DMODEL; k0 += 32) {
#pragma unroll
        for (int c = 0; c < 2; c++) {
            const int chunk = c * 256 + t;
            const int row   = chunk >> 2;
            const int col   = (chunk & 3) * 8;
            const bf16_t* gA = A + (size_t)(mBase + row) * DMODEL + k0 + col;
            bf16_t* lA = As + (c * 256 + wave * 64) * 8;
            __builtin_amdgcn_global_load_lds(
                (const __attribute__((address_space(1))) void*)gA,
                (__attribute__((address_space(3))) void*)lA, 16, 0, 0);
        }
        {
            const int row = t >> 2;
            const int col = (t & 3) * 8;
            const bf16_t* gB = W + (size_t)(nBase + row) * DMODEL + k0 + col;
            bf16_t* lB = Bs + (wave * 64) * 8;
            __builtin_amdgcn_global_load_lds(
                (const __attribute__((address_space(1))) void*)gB,
                (__attribute__((address_space(3))) void*)lB, 16, 0, 0);
        }
        __syncthreads();

        bf16x8 af[2], bfr[4];
#pragma unroll
        for (int mi = 0; mi < 2; mi++)
            af[mi] = *(const bf16x8*)(As + (wRow + mi * 16 + l15) * 32 + quad * 8);
#pragma unroll
        for (int ni = 0; ni < 4; ni++)
            bfr[ni] = *(const bf16x8*)(Bs + (ni * 16 + l15) * 32 + quad * 8);
#pragma unroll
        for (int mi = 0; mi < 2; mi++)
#pragma unroll
            for (int ni = 0; ni < 4; ni++)
                acc[mi][ni] = __builtin_amdgcn_mfma_f32_16x16x32_bf16(
                    af[mi], bfr[ni], acc[mi][ni], 0, 0, 0);
        __syncthreads();
    }

    float bvv[4];
#pragma unroll
    for (int ni = 0; ni < 4; ni++)
        bvv[ni] = bias[nBase + ni * 16 + l15];

#pragma unroll
    for (int mi = 0; mi < 2; mi++) {
#pragma unroll
        for (int ni = 0; ni < 4; ni++) {
            const int n = nBase + ni * 16 + l15;
#pragma unroll
            for (int j = 0; j < 4; j++) {
                const int m = mBase + wRow + mi * 16 + quad * 4 + j;
                C[(size_t)m * DMODEL + n] = acc[mi][ni][j] + bvv[ni];
            }
        }
    }
}

// ---------------------------------------------------------------------------
// Launch. Workspace (bf16 elems): cvt region [q|k|v|wq|wk|wv|wo] (16M),
// q_ws|k_ws|v_ws (12M), o_ws aliases q_bf, lens int[2]. Total ~56 MB.
// ---------------------------------------------------------------------------
extern "C" void kernel_launch(void* const* d_in, const int* in_sizes, int n_in,
                              void* d_out, int out_size, void* d_ws, size_t ws_size,
                              hipStream_t stream)
{
    const float* query = (const float*)d_in[0];
    const float* key   = (const float*)d_in[1];
    const float* value = (const float*)d_in[2];
    const float* Wq = (const float*)d_in[3];
    const float* bq = (const float*)d_in[4];
    const float* Wk = (const float*)d_in[5];
    const float* bk = (const float*)d_in[6];
    const float* Wv = (const float*)d_in[7];
    const float* bv = (const float*)d_in[8];
    const float* Wo = (const float*)d_in[9];
    const float* bo = (const float*)d_in[10];
    const unsigned char* am  = (const unsigned char*)d_in[11];
    const unsigned char* kpm = (const unsigned char*)d_in[12];

    bf16_t* cvt   = (bf16_t*)d_ws;
    bf16_t* q_bf  = cvt;
    bf16_t* wq_bf = cvt + 3 * SEG;
    bf16_t* wo_bf = wq_bf + 3 * WSEG;
    bf16_t* q_ws  = cvt + CVT_TOT;
    bf16_t* k_ws  = q_ws + SEG;
    bf16_t* v_ws  = k_ws + SEG;
    bf16_t* o_ws  = q_bf;                    // alias: q_bf dead after QKV GEMM
    int*    lens  = (int*)(v_ws + SEG);

    prep_lens<<<1, 256, 0, stream>>>(am, kpm, lens);
    cvt_all<<<4096, 256, 0, stream>>>(query, key, value, Wq, Wk, Wv, Wo, cvt);

    gemm_qkv<<<dim3(DMODEL / 128, (S_LEN * BATCH) / 128, 3), dim3(256), 0, stream>>>(
        q_bf, wq_bf, bq, bk, bv, q_ws);

    attn<<<dim3(S_LEN / 64, BATCH * NHEAD), dim3(256), 0, stream>>>(
        q_ws, k_ws, v_ws, o_ws, lens);

    gemm_o<<<dim3(DMODEL / 64, (S_LEN * BATCH) / 128), dim3(256), 0, stream>>>(
        o_ws, wo_bf, bo, (float*)d_out);
}

// Round 4
// 298.729 us; speedup vs baseline: 1.2487x; 1.1971x over previous
//
#include <hip/hip_runtime.h>
#include <hip/hip_bf16.h>

// Problem constants (MultiHeadAttention: S=2048, B=2, D=1024, H=16, dk=64)
#define S_LEN 2048
#define BATCH 2
#define DMODEL 1024
#define NHEAD 16
#define DK 64

typedef __bf16 bf16_t;
typedef bf16_t bf16x4 __attribute__((ext_vector_type(4)));
typedef bf16_t bf16x8 __attribute__((ext_vector_type(8)));
typedef float floatx4 __attribute__((ext_vector_type(4)));

#define SEG  ((size_t)S_LEN * BATCH * DMODEL)   // 4,194,304
#define WSEG ((size_t)DMODEL * DMODEL)          // 1,048,576
#define CVT_TOT (3 * SEG + 4 * WSEG)            // 16,777,216

// Q pre-scale: 1/sqrt(dk) * log2(e)  -> softmax uses exp2 directly
#define QSCALE 0.180336879f

// ---------------------------------------------------------------------------
// Kernel 0: mask dtype sniff + per-batch valid lengths.
// ---------------------------------------------------------------------------
__global__ void prep_lens(const unsigned char* __restrict__ am,
                          const unsigned char* __restrict__ kpm,
                          int* __restrict__ lens)
{
    __shared__ int stride_s;
    __shared__ int cnt[BATCH];
    const int t = threadIdx.x;
    if (t == 0) {
        int st;
        if (am[1]) st = 1;
        else if (am[2] | am[3]) st = 2;
        else st = 4;
        stride_s = st;
    }
    if (t < BATCH) cnt[t] = 0;
    __syncthreads();
    const int st = stride_s;
    for (int idx = t; idx < BATCH * S_LEN; idx += blockDim.x) {
        int nz = 0;
        for (int c = 0; c < st; c++) nz |= kpm[idx * st + c];
        if (nz) atomicAdd(&cnt[idx / S_LEN], 1);
    }
    __syncthreads();
    if (t < BATCH) lens[t] = S_LEN - cnt[t];
}

// ---------------------------------------------------------------------------
// Kernel 1: f32 -> bf16 conversion of q,k,v,Wq,Wk,Wv,Wo into workspace.
// ---------------------------------------------------------------------------
__global__ void cvt_all(const float* __restrict__ q, const float* __restrict__ k,
                        const float* __restrict__ v, const float* __restrict__ wq,
                        const float* __restrict__ wk, const float* __restrict__ wv,
                        const float* __restrict__ wo, bf16_t* __restrict__ out)
{
    size_t i4 = ((size_t)blockIdx.x * blockDim.x + threadIdx.x) * 4;
    const size_t stride = (size_t)gridDim.x * blockDim.x * 4;
    for (; i4 < CVT_TOT; i4 += stride) {
        const float* src;
        size_t off;
        if (i4 < SEG)                    { src = q;  off = i4; }
        else if (i4 < 2 * SEG)           { src = k;  off = i4 - SEG; }
        else if (i4 < 3 * SEG)           { src = v;  off = i4 - 2 * SEG; }
        else if (i4 < 3 * SEG + WSEG)    { src = wq; off = i4 - 3 * SEG; }
        else if (i4 < 3 * SEG + 2 * WSEG){ src = wk; off = i4 - (3 * SEG + WSEG); }
        else if (i4 < 3 * SEG + 3 * WSEG){ src = wv; off = i4 - (3 * SEG + 2 * WSEG); }
        else                             { src = wo; off = i4 - (3 * SEG + 3 * WSEG); }
        const float4 x = *(const float4*)(src + off);
        bf16x4 r;
        r[0] = (bf16_t)x.x; r[1] = (bf16_t)x.y; r[2] = (bf16_t)x.z; r[3] = (bf16_t)x.w;
        *(bf16x4*)(out + i4) = r;
    }
}

// ---------------------------------------------------------------------------
// Fused Q/K/V projection GEMM. grid = (8, 32, 3); z selects {Q,K,V}.
// z<2  -> scatter [B,H,S,dk] (Q gets QSCALE fold); z==2 -> [B,H,dk,S] (V^T).
// 128x128 tile, 4 waves, BK=32, global_load_lds width-16 staging (m97).
// ---------------------------------------------------------------------------
__global__ __launch_bounds__(256, 2)
void gemm_qkv(const bf16_t* __restrict__ Abase, const bf16_t* __restrict__ Wbase,
              const float* __restrict__ bq, const float* __restrict__ bk,
              const float* __restrict__ bv, bf16_t* __restrict__ Obase)
{
    __shared__ bf16_t As[128 * 32];
    __shared__ bf16_t Bs[128 * 32];

    const int z = blockIdx.z;
    const bf16_t* A = Abase + (size_t)z * SEG;
    const bf16_t* W = Wbase + (size_t)z * WSEG;
    const float* bias = (z == 0) ? bq : (z == 1) ? bk : bv;
    bf16_t* C = Obase + (size_t)z * SEG;

    const int t    = threadIdx.x;
    const int wave = t >> 6;
    const int lane = t & 63;
    const int l15  = lane & 15;
    const int quad = lane >> 4;

    const int mBase = blockIdx.y * 128;
    const int nBase = blockIdx.x * 128;
    const int wRow  = (wave >> 1) * 64;
    const int wCol  = (wave & 1) * 64;

    floatx4 acc[4][4];
#pragma unroll
    for (int i = 0; i < 4; i++)
#pragma unroll
        for (int j = 0; j < 4; j++) acc[i][j] = (floatx4){0.f, 0.f, 0.f, 0.f};

    for (int k0 = 0; k0 < DMODEL; k0 += 32) {
#pragma unroll
        for (int c = 0; c < 2; c++) {
            const int chunk = c * 256 + t;
            const int row   = chunk >> 2;
            const int col   = (chunk & 3) * 8;
            const bf16_t* gA = A + (size_t)(mBase + row) * DMODEL + k0 + col;
            const bf16_t* gB = W + (size_t)(nBase + row) * DMODEL + k0 + col;
            bf16_t* lA = As + (c * 256 + wave * 64) * 8;
            bf16_t* lB = Bs + (c * 256 + wave * 64) * 8;
            __builtin_amdgcn_global_load_lds(
                (const __attribute__((address_space(1))) void*)gA,
                (__attribute__((address_space(3))) void*)lA, 16, 0, 0);
            __builtin_amdgcn_global_load_lds(
                (const __attribute__((address_space(1))) void*)gB,
                (__attribute__((address_space(3))) void*)lB, 16, 0, 0);
        }
        __syncthreads();

        bf16x8 af[4], bfr[4];
#pragma unroll
        for (int mi = 0; mi < 4; mi++)
            af[mi] = *(const bf16x8*)(As + (wRow + mi * 16 + l15) * 32 + quad * 8);
#pragma unroll
        for (int ni = 0; ni < 4; ni++)
            bfr[ni] = *(const bf16x8*)(Bs + (wCol + ni * 16 + l15) * 32 + quad * 8);
#pragma unroll
        for (int mi = 0; mi < 4; mi++)
#pragma unroll
            for (int ni = 0; ni < 4; ni++)
                acc[mi][ni] = __builtin_amdgcn_mfma_f32_16x16x32_bf16(
                    af[mi], bfr[ni], acc[mi][ni], 0, 0, 0);
        __syncthreads();
    }

    const float scale = (z == 0) ? QSCALE : 1.0f;
    float bvv[4];
#pragma unroll
    for (int ni = 0; ni < 4; ni++)
        bvv[ni] = bias[nBase + wCol + ni * 16 + l15];

#pragma unroll
    for (int mi = 0; mi < 4; mi++) {
#pragma unroll
        for (int ni = 0; ni < 4; ni++) {
            const int n = nBase + wCol + ni * 16 + l15;
            const int h = n >> 6, i = n & 63;
#pragma unroll
            for (int j = 0; j < 4; j++) {
                const int m = mBase + wRow + mi * 16 + quad * 4 + j;
                const int s = m >> 1, b = m & 1;       // m = s*B + b, B=2
                const float v = (acc[mi][ni][j] + bvv[ni]) * scale;
                size_t off;
                if (z < 2)
                    off = ((size_t)(b * NHEAD + h) * S_LEN + s) * DK + i;
                else
                    off = ((size_t)(b * NHEAD + h) * DK + i) * S_LEN + s;
                C[off] = (bf16_t)v;
            }
        }
    }
}

// ---------------------------------------------------------------------------
// Flash-style causal attention, TRANSPOSED-SCORE scheme.
// Grid (16, B*H): block bx processes qTile 31-bx then bx (33-34 iters, flat).
// 4 waves x 16 q-rows. S^T = K*Q^T via operand-swapped MFMA so each lane
// owns one q row x 16 keys -> softmax reductions are in-register + 2
// cross-quad shuffles. P roundtrips LDS (C-layout -> A-layout). Q pre-scaled
// by QSCALE -> exp2 softmax. LDS rows padded to 72 bf16 (conflict-free).
// ---------------------------------------------------------------------------
__global__ __launch_bounds__(256, 2)
void attn(const bf16_t* __restrict__ qw, const bf16_t* __restrict__ kw,
          const bf16_t* __restrict__ vw, bf16_t* __restrict__ ow,
          const int* __restrict__ lens)
{
    __shared__ bf16_t Ks[64 * 72];          // [key][dk], padded
    __shared__ bf16_t Vs[64 * 72];          // [dk][key], padded
    __shared__ bf16_t Ps[4 * 16 * 72];      // per-wave P scratch [q][key]

    const int t    = threadIdx.x;
    const int wave = t >> 6;
    const int lane = t & 63;
    const int l15  = lane & 15;
    const int quad = lane >> 4;
    const int qg   = lane & 48;             // quad group base
    const int rowbase = qg >> 2;            // quad*4

    const int bh  = blockIdx.y;
    const int b   = bh >> 4;
    const int len = lens[b];

    const bf16_t* kbase = kw + (size_t)bh * S_LEN * DK;
    const bf16_t* vbase = vw + (size_t)bh * DK * S_LEN;

    for (int ti = 0; ti < 2; ti++) {
        const int qTile = ti ? blockIdx.x : (31 - (int)blockIdx.x);
        const int qBase = qTile * 64;

        // Q fragments (A-layout: [m=l15][k=quad*8+j]); also serves as B-frag
        // of the swapped MFMA (B[k][n]: n=l15).
        const bf16_t* Qg = qw + ((size_t)bh * S_LEN + qBase + wave * 16) * DK;
        const bf16x8 qa0 = *(const bf16x8*)(Qg + l15 * DK + quad * 8);
        const bf16x8 qa1 = *(const bf16x8*)(Qg + l15 * DK + 32 + quad * 8);

        floatx4 O[4];
#pragma unroll
        for (int i = 0; i < 4; i++) O[i] = (floatx4){0.f, 0.f, 0.f, 0.f};
        float mrow = -3.0e38f, lrow = 0.f;   // per-lane: q = qBase+wave*16+l15

        const int ktEnd = min(qTile, (len - 1) >> 6);

        int4 kreg[2], vreg[2];
#pragma unroll
        for (int c = 0; c < 2; c++) {       // prefetch tile 0
            const int idx = c * 256 + t;
            kreg[c] = *(const int4*)(kbase + (size_t)idx * 8);
            vreg[c] = *(const int4*)(vbase + (size_t)(idx >> 3) * S_LEN + (idx & 7) * 8);
        }

        for (int kt = 0; kt <= ktEnd; kt++) {
            const int ktBase = kt * 64;
#pragma unroll
            for (int c = 0; c < 2; c++) {
                const int idx = c * 256 + t, row = idx >> 3, col = (idx & 7) * 8;
                *(int4*)(Ks + row * 72 + col) = kreg[c];
                *(int4*)(Vs + row * 72 + col) = vreg[c];
            }
            __syncthreads();

            if (kt < ktEnd) {               // prefetch next tile
                const int nb = ktBase + 64;
#pragma unroll
                for (int c = 0; c < 2; c++) {
                    const int idx = c * 256 + t;
                    kreg[c] = *(const int4*)(kbase + (size_t)nb * DK + idx * 8);
                    vreg[c] = *(const int4*)(vbase + (size_t)(idx >> 3) * S_LEN + nb + (idx & 7) * 8);
                }
            }

            // S^T tiles: mfma(K_frag, Q_frag) -> C[m=key][n=q], n=l15
            floatx4 sc[4];
#pragma unroll
            for (int ni = 0; ni < 4; ni++) {
                const bf16x8 kf0 = *(const bf16x8*)(Ks + (ni * 16 + l15) * 72 + quad * 8);
                const bf16x8 kf1 = *(const bf16x8*)(Ks + (ni * 16 + l15) * 72 + 32 + quad * 8);
                floatx4 zz = (floatx4){0.f, 0.f, 0.f, 0.f};
                zz = __builtin_amdgcn_mfma_f32_16x16x32_bf16(kf0, qa0, zz, 0, 0, 0);
                zz = __builtin_amdgcn_mfma_f32_16x16x32_bf16(kf1, qa1, zz, 0, 0, 0);
                sc[ni] = zz;
            }

            // mask + per-lane max over 16 keys (lane owns q = qBase+wave*16+l15)
            const int q = qBase + wave * 16 + l15;
            const bool needMask = (kt == qTile) || (ktBase + 64 > len);
            if (needMask) {
#pragma unroll
                for (int ni = 0; ni < 4; ni++) {
#pragma unroll
                    for (int r = 0; r < 4; r++) {
                        const int key = ktBase + ni * 16 + quad * 4 + r;
                        if (key > q || key >= len) sc[ni][r] = -3.0e38f;
                    }
                }
            }
            floatx4 mx4 = sc[0];
#pragma unroll
            for (int ni = 1; ni < 4; ni++) {
                mx4[0] = fmaxf(mx4[0], sc[ni][0]); mx4[1] = fmaxf(mx4[1], sc[ni][1]);
                mx4[2] = fmaxf(mx4[2], sc[ni][2]); mx4[3] = fmaxf(mx4[3], sc[ni][3]);
            }
            float tmax = fmaxf(fmaxf(mx4[0], mx4[1]), fmaxf(mx4[2], mx4[3]));
            tmax = fmaxf(tmax, __shfl_xor(tmax, 16));
            tmax = fmaxf(tmax, __shfl_xor(tmax, 32));

            const float mnew = fmaxf(mrow, tmax);
            const float alpha = exp2f(mrow - mnew);
            mrow = mnew;

            float rsum = 0.f;
#pragma unroll
            for (int ni = 0; ni < 4; ni++) {
#pragma unroll
                for (int r = 0; r < 4; r++) {
                    const float p = exp2f(sc[ni][r] - mrow);
                    sc[ni][r] = p;
                    rsum += p;
                }
            }
            rsum += __shfl_xor(rsum, 16);
            rsum += __shfl_xor(rsum, 32);
            lrow = lrow * alpha + rsum;

            // broadcast alpha to C-layout rows (q-row = quad*4+j lives at l15=quad*4+j)
            float aj[4];
#pragma unroll
            for (int j = 0; j < 4; j++)
                aj[j] = __shfl(alpha, qg | (rowbase + j));
#pragma unroll
            for (int nd = 0; nd < 4; nd++)
#pragma unroll
                for (int j = 0; j < 4; j++) O[nd][j] *= aj[j];

            // P store: lane has [q=l15][key=ktBase+ni*16+quad*4+r] -> packed b64
            bf16_t* Pw = Ps + wave * 16 * 72;
#pragma unroll
            for (int ni = 0; ni < 4; ni++) {
                bf16x4 pk;
                pk[0] = (bf16_t)sc[ni][0]; pk[1] = (bf16_t)sc[ni][1];
                pk[2] = (bf16_t)sc[ni][2]; pk[3] = (bf16_t)sc[ni][3];
                *(bf16x4*)(Pw + l15 * 72 + ni * 16 + quad * 4) = pk;
            }

            const bf16x8 pa0 = *(const bf16x8*)(Pw + l15 * 72 + quad * 8);
            const bf16x8 pa1 = *(const bf16x8*)(Pw + l15 * 72 + 32 + quad * 8);
#pragma unroll
            for (int nd = 0; nd < 4; nd++) {
                const bf16x8 vb0 = *(const bf16x8*)(Vs + (nd * 16 + l15) * 72 + quad * 8);
                const bf16x8 vb1 = *(const bf16x8*)(Vs + (nd * 16 + l15) * 72 + 32 + quad * 8);
                O[nd] = __builtin_amdgcn_mfma_f32_16x16x32_bf16(pa0, vb0, O[nd], 0, 0, 0);
                O[nd] = __builtin_amdgcn_mfma_f32_16x16x32_bf16(pa1, vb1, O[nd], 0, 0, 0);
            }
            __syncthreads();   // protect Ks/Vs before next fill
        }

        // fetch lrow for C-layout rows, write O to [S, B, D]
        float rinv[4];
#pragma unroll
        for (int j = 0; j < 4; j++)
            rinv[j] = 1.0f / __shfl(lrow, qg | (rowbase + j));
#pragma unroll
        for (int nd = 0; nd < 4; nd++) {
            const int d = (bh & 15) * DK + nd * 16 + l15;
#pragma unroll
            for (int j = 0; j < 4; j++) {
                const int qq = qBase + wave * 16 + quad * 4 + j;
                ow[((size_t)qq * BATCH + b) * DMODEL + d] = (bf16_t)(O[nd][j] * rinv[j]);
            }
        }
        __syncthreads();       // Ks/Vs reused by second tile
    }
}

// ---------------------------------------------------------------------------
// Output projection GEMM, 128x64 tiles -> 512 blocks (2/CU).
// ---------------------------------------------------------------------------
__global__ __launch_bounds__(256, 2)
void gemm_o(const bf16_t* __restrict__ A, const bf16_t* __restrict__ W,
            const float* __restrict__ bias, float* __restrict__ C)
{
    __shared__ bf16_t As[128 * 32];
    __shared__ bf16_t Bs[64 * 32];

    const int t    = threadIdx.x;
    const int wave = t >> 6;
    const int lane = t & 63;
    const int l15  = lane & 15;
    const int quad = lane >> 4;

    const int mBase = blockIdx.y * 128;
    const int nBase = blockIdx.x * 64;
    const int wRow  = wave * 32;

    floatx4 acc[2][4];
#pragma unroll
    for (int i = 0; i < 2; i++)
#pragma unroll
        for (int j = 0; j < 4; j++) acc[i][j] = (floatx4){0.f, 0.f, 0.f, 0.f};

    for (int k0 = 0; k0 < DMODEL; k0 += 32) {
#pragma unroll
        for (int c = 0; c < 2; c++) {
            const int chunk = c * 256 + t;
            const int row   = chunk >> 2;
            const int col   = (chunk & 3) * 8;
            const bf16_t* gA = A + (size_t)(mBase + row) * DMODEL + k0 + col;
            bf16_t* lA = As + (c * 256 + wave * 64) * 8;
            __builtin_amdgcn_global_load_lds(
                (const __attribute__((address_space(1))) void*)gA,
                (__attribute__((address_space(3))) void*)lA, 16, 0, 0);
        }
        {
            const int row = t >> 2;
            const int col = (t & 3) * 8;
            const bf16_t* gB = W + (size_t)(nBase + row) * DMODEL + k0 + col;
            bf16_t* lB = Bs + (wave * 64) * 8;
            __builtin_amdgcn_global_load_lds(
                (const __attribute__((address_space(1))) void*)gB,
                (__attribute__((address_space(3))) void*)lB, 16, 0, 0);
        }
        __syncthreads();

        bf16x8 af[2], bfr[4];
#pragma unroll
        for (int mi = 0; mi < 2; mi++)
            af[mi] = *(const bf16x8*)(As + (wRow + mi * 16 + l15) * 32 + quad * 8);
#pragma unroll
        for (int ni = 0; ni < 4; ni++)
            bfr[ni] = *(const bf16x8*)(Bs + (ni * 16 + l15) * 32 + quad * 8);
#pragma unroll
        for (int mi = 0; mi < 2; mi++)
#pragma unroll
            for (int ni = 0; ni < 4; ni++)
                acc[mi][ni] = __builtin_amdgcn_mfma_f32_16x16x32_bf16(
                    af[mi], bfr[ni], acc[mi][ni], 0, 0, 0);
        __syncthreads();
    }

    float bvv[4];
#pragma unroll
    for (int ni = 0; ni < 4; ni++)
        bvv[ni] = bias[nBase + ni * 16 + l15];

#pragma unroll
    for (int mi = 0; mi < 2; mi++) {
#pragma unroll
        for (int ni = 0; ni < 4; ni++) {
            const int n = nBase + ni * 16 + l15;
#pragma unroll
            for (int j = 0; j < 4; j++) {
                const int m = mBase + wRow + mi * 16 + quad * 4 + j;
                C[(size_t)m * DMODEL + n] = acc[mi][ni][j] + bvv[ni];
            }
        }
    }
}

// ---------------------------------------------------------------------------
// Launch. Workspace (bf16 elems): cvt region [q|k|v|wq|wk|wv|wo] (16M),
// q_ws|k_ws|v_ws (12M), o_ws aliases q_bf, lens int[2]. Total ~56 MB.
// ---------------------------------------------------------------------------
extern "C" void kernel_launch(void* const* d_in, const int* in_sizes, int n_in,
                              void* d_out, int out_size, void* d_ws, size_t ws_size,
                              hipStream_t stream)
{
    const float* query = (const float*)d_in[0];
    const float* key   = (const float*)d_in[1];
    const float* value = (const float*)d_in[2];
    const float* Wq = (const float*)d_in[3];
    const float* bq = (const float*)d_in[4];
    const float* Wk = (const float*)d_in[5];
    const float* bk = (const float*)d_in[6];
    const float* Wv = (const float*)d_in[7];
    const float* bv = (const float*)d_in[8];
    const float* Wo = (const float*)d_in[9];
    const float* bo = (const float*)d_in[10];
    const unsigned char* am  = (const unsigned char*)d_in[11];
    const unsigned char* kpm = (const unsigned char*)d_in[12];

    bf16_t* cvt   = (bf16_t*)d_ws;
    bf16_t* q_bf  = cvt;
    bf16_t* wq_bf = cvt + 3 * SEG;
    bf16_t* wo_bf = wq_bf + 3 * WSEG;
    bf16_t* q_ws  = cvt + CVT_TOT;
    bf16_t* k_ws  = q_ws + SEG;
    bf16_t* v_ws  = k_ws + SEG;
    bf16_t* o_ws  = q_bf;                    // alias: q_bf dead after QKV GEMM
    int*    lens  = (int*)(v_ws + SEG);

    prep_lens<<<1, 256, 0, stream>>>(am, kpm, lens);
    cvt_all<<<4096, 256, 0, stream>>>(query, key, value, Wq, Wk, Wv, Wo, cvt);

    gemm_qkv<<<dim3(DMODEL / 128, (S_LEN * BATCH) / 128, 3), dim3(256), 0, stream>>>(
        q_bf, wq_bf, bq, bk, bv, q_ws);

    attn<<<dim3(16, BATCH * NHEAD), dim3(256), 0, stream>>>(
        q_ws, k_ws, v_ws, o_ws, lens);

    gemm_o<<<dim3(DMODEL / 64, (S_LEN * BATCH) / 128), dim3(256), 0, stream>>>(
        o_ws, wo_bf, bo, (float*)d_out);
}